// Round 1
// baseline (282.305 us; speedup 1.0000x reference)
//
#include <hip/hip_runtime.h>

// Fully fused DynamicLinearModel kernel.
//
// theta_t = a*theta_{t-1} + c_{t-1},  a = sigmoid(G), c = Z@gamma, theta_0 = 0
// out_t   = theta_t + X_t@eta + Z_t@zeta
//
// Chunks of CHUNK rows are fully independent thanks to a WIN-row geometric
// lookback: a < sigmoid(1) = 0.7311 => a^63 < 3e-9, far below f32 noise.
// Each block recomputes c for its window, so there is NO inter-kernel
// dependency, NO workspace, and every d_out element is written exactly once.
//
// CHUNK=256 (SEG=1): nblk ~= 1954 -> ~7816 waves, ~95% occupancy cap
// (vs 489 blocks / 24% cap at CHUNK=1024, which left the chip latency-bound
// at 16% HBM). Window re-reads overlap adjacent blocks -> L2/L3 hits.

#define WIN    64
#define CHUNK  256
#define RPI    64                                  // rows per block-iteration
#define NITER  ((WIN + CHUNK) / RPI)               // 5

__global__ __launch_bounds__(256) void dlm_fused(
    const float* __restrict__ X, const float* __restrict__ Z,
    const float* __restrict__ Gp,
    const float* __restrict__ eta, const float* __restrict__ zeta,
    const float* __restrict__ gam,
    float* __restrict__ out, int T)
{
    const int tid  = threadIdx.x;
    const int lane = tid & 63;
    const int wv   = tid >> 6;        // wave 0..3
    const int sub  = lane & 15;       // float4 index within a 64-float row
    const int rsub = lane >> 4;       // row group within the wave (0..3)
    const int s    = (int)blockIdx.x * CHUNK;

    __shared__ float cl[WIN + CHUNK]; // c for rows [s-WIN, s+CHUNK)
    __shared__ float bl[CHUNK];       // base for rows [s, s+CHUNK)
    __shared__ float sc[256];
    __shared__ float theta_sh;

    const float4 e4  = ((const float4*)eta)[sub];
    const float4 sz4 = ((const float4*)zeta)[sub];
    const float4 g4  = ((const float4*)gam)[sub];
    const float4* X4 = (const float4*)X;
    const float4* Z4 = (const float4*)Z;

    const float g   = *Gp;
    const float a   = 1.0f / (1.0f + expf(-g));
    const float l2a = log2f(a);

    // ---- row loop: iteration i covers rows [s-WIN+i*64, s-WIN+(i+1)*64).
    // i == 0 is the pure lookback window (c only, no X / base).
    // 16 lanes per row (perfect 1KB coalescing), 8 loads in flight per thread.
    for (int i = 0; i < NITER; ++i) {
        const int rb = s - WIN + i * RPI + wv * 16;
        float cp[4], bp[4];
        #pragma unroll
        for (int u = 0; u < 4; ++u) {
            const int r = rb + u * 4 + rsub;
            float4 z = make_float4(0.f, 0.f, 0.f, 0.f);
            float4 x = make_float4(0.f, 0.f, 0.f, 0.f);
            const bool in = (r >= 0) && (r < T);
            if (in)           z = Z4[(size_t)r * 16 + sub];
            if (in && i > 0)  x = X4[(size_t)r * 16 + sub];
            cp[u] = z.x*g4.x + z.y*g4.y + z.z*g4.z + z.w*g4.w;
            bp[u] = x.x*e4.x + x.y*e4.y + x.z*e4.z + x.w*e4.w
                  + z.x*sz4.x + z.y*sz4.y + z.z*sz4.z + z.w*sz4.w;
        }
        #pragma unroll
        for (int u = 0; u < 4; ++u) {
            #pragma unroll
            for (int off = 1; off <= 8; off <<= 1) {   // reduce within 16 lanes
                cp[u] += __shfl_xor(cp[u], off, 64);
                bp[u] += __shfl_xor(bp[u], off, 64);
            }
        }
        if (sub == 0) {
            #pragma unroll
            for (int u = 0; u < 4; ++u) {
                const int r = rb + u * 4 + rsub;
                cl[r - s + WIN] = cp[u];          // rows >= T wrote 0
                if (i > 0) bl[r - s] = bp[u];
            }
        }
    }
    __syncthreads();

    // ---- incoming state: theta_{s-1} = sum_{j=0..WIN-2} a^j * c[s-2-j]
    if (tid < 64) {
        float term = 0.0f;
        if (tid <= WIN - 2)
            term = exp2f((float)tid * l2a) * cl[WIN - 2 - tid];
        #pragma unroll
        for (int off = 1; off <= 32; off <<= 1)
            term += __shfl_xor(term, off, 64);
        if (tid == 0) theta_sh = term;
    }

    // ---- per-thread value (SEG=1): v_t = c[t-1], v_0 = 0
    const int t = s + tid;
    const float v = (t == 0) ? 0.0f : cl[WIN + tid - 1];
    sc[tid] = v;
    __syncthreads();
    const float theta_in = theta_sh;

    // ---- inclusive Hillis-Steele scan, ratio a (squares each step)
    float Ad = a;
    for (int d = 1; d < 256; d <<= 1) {
        const float self = sc[tid];
        const float prev = (tid >= d) ? sc[tid - d] : 0.0f;
        __syncthreads();
        sc[tid] = self + Ad * prev;
        __syncthreads();
        Ad *= Ad;
    }

    // ---- emit: theta_t = a^{tid+1} theta_in + S_tid, coalesced scalar store
    const float E = (tid > 0) ? sc[tid - 1] : 0.0f;
    float theta = exp2f((float)tid * l2a) * theta_in + E;
    theta = a * theta + v;
    if (t < T) out[t] = bl[tid] + theta;
}

extern "C" void kernel_launch(void* const* d_in, const int* in_sizes, int n_in,
                              void* d_out, int out_size, void* d_ws, size_t ws_size,
                              hipStream_t stream) {
    const float* X     = (const float*)d_in[0];
    const float* Z     = (const float*)d_in[1];
    const float* G     = (const float*)d_in[2];
    const float* eta   = (const float*)d_in[3];
    const float* zeta  = (const float*)d_in[4];
    const float* gamma = (const float*)d_in[5];
    float* out = (float*)d_out;

    const int T = in_sizes[0] / 64;
    const int nblk = (T + CHUNK - 1) / CHUNK;

    dlm_fused<<<nblk, 256, 0, stream>>>(X, Z, G, eta, zeta, gamma, out, T);
}

// Round 3
// 279.341 us; speedup vs baseline: 1.0106x; 1.0106x over previous
//
#include <hip/hip_runtime.h>

// DynamicLinearModel, two-pass version.  (Round-2 resubmit: round 2's bench
// was an infra failure — "container failed twice", no counters, no verdict.)
//
// theta_t = a*theta_{t-1} + c_{t-1},  a = sigmoid(G), c = Z@gamma, theta_0 = 0
// out_t   = theta_t + X_t@eta + Z_t@zeta
//
// Round-1 evidence: the fused kernel is service-rate-capped at ~2.6 TB/s
// effective (dur invariant under 4x occupancy change -> not a parallelism
// problem). This version isolates the 256 MB streaming phase into a pure
// m13-style stream kernel (pass 1) and does the scan in a tiny second
// kernel over the materialized c/b arrays (6 MB total traffic).
//
// Pass 1: c[t] = Z[t].gamma -> ws;  b[t] = X[t].eta + Z[t].zeta -> out
// Pass 2: block-local scan over c (64-row geometric lookback, a^63 < 3e-9),
//         out[t] = b[t] + theta_t.  No window recompute: c is materialized.

#define WIN    64
#define CHUNK  256

// ---------------------------------------------------------------------------
// Pass 1: pure streaming GEMV. 16 lanes per row (1 KB coalesced wave-loads),
// 8 float4 loads forced in flight per thread, single barrier, coalesced store.
// ---------------------------------------------------------------------------
__global__ __launch_bounds__(256) void dlm_pass1(
    const float* __restrict__ X, const float* __restrict__ Z,
    const float* __restrict__ eta, const float* __restrict__ zeta,
    const float* __restrict__ gam,
    float* __restrict__ c_ws, float* __restrict__ b_out, int T)
{
    const int tid  = threadIdx.x;
    const int lane = tid & 63;
    const int wv   = tid >> 6;        // wave 0..3
    const int sub  = lane & 15;       // float4 index within a 64-float row
    const int rsub = lane >> 4;       // row within the 4-row group
    const int s    = (int)blockIdx.x * CHUNK;

    __shared__ float cl[CHUNK];
    __shared__ float bl[CHUNK];

    const float4 e4  = ((const float4*)eta)[sub];
    const float4 sz4 = ((const float4*)zeta)[sub];
    const float4 g4  = ((const float4*)gam)[sub];
    const float4* X4 = (const float4*)X;
    const float4* Z4 = (const float4*)Z;

    #pragma unroll
    for (int i = 0; i < CHUNK / 64; ++i) {
        const int rb = s + i * 64 + wv * 16;
        float4 zz[4], xx[4];
        #pragma unroll
        for (int u = 0; u < 4; ++u) {          // all 8 loads issued up front
            const int r = rb + u * 4 + rsub;
            const bool in = (r < T);
            zz[u] = in ? Z4[(size_t)r * 16 + sub] : make_float4(0.f, 0.f, 0.f, 0.f);
            xx[u] = in ? X4[(size_t)r * 16 + sub] : make_float4(0.f, 0.f, 0.f, 0.f);
        }
        float cp[4], bp[4];
        #pragma unroll
        for (int u = 0; u < 4; ++u) {
            cp[u] = zz[u].x*g4.x + zz[u].y*g4.y + zz[u].z*g4.z + zz[u].w*g4.w;
            bp[u] = xx[u].x*e4.x + xx[u].y*e4.y + xx[u].z*e4.z + xx[u].w*e4.w
                  + zz[u].x*sz4.x + zz[u].y*sz4.y + zz[u].z*sz4.z + zz[u].w*sz4.w;
        }
        #pragma unroll
        for (int u = 0; u < 4; ++u) {
            #pragma unroll
            for (int off = 1; off <= 8; off <<= 1) {   // reduce within 16 lanes
                cp[u] += __shfl_xor(cp[u], off, 64);
                bp[u] += __shfl_xor(bp[u], off, 64);
            }
        }
        if (sub == 0) {
            #pragma unroll
            for (int u = 0; u < 4; ++u) {
                const int idx = i * 64 + wv * 16 + u * 4 + rsub;
                cl[idx] = cp[u];
                bl[idx] = bp[u];
            }
        }
    }
    __syncthreads();

    const int t = s + tid;
    if (t < T) {
        c_ws[t]  = cl[tid];
        b_out[t] = bl[tid];
    }
}

// ---------------------------------------------------------------------------
// Pass 2: per-block scan over materialized c. Reads c window directly from
// global (hot in L2/L3 from pass 1).
// ---------------------------------------------------------------------------
__global__ __launch_bounds__(256) void dlm_pass2(
    const float* __restrict__ c, const float* __restrict__ Gp,
    float* __restrict__ out, int T)
{
    const int tid = threadIdx.x;
    const int s   = (int)blockIdx.x * CHUNK;
    const int t   = s + tid;

    __shared__ float sc[CHUNK];
    __shared__ float theta_sh;

    const float g   = *Gp;
    const float a   = 1.0f / (1.0f + expf(-g));
    const float l2a = log2f(a);

    // v_t = c[t-1], v_0 = 0; b read up front (own element only, no hazard)
    const float v = (t >= 1 && t < T) ? c[t - 1] : 0.0f;
    const float b = (t < T) ? out[t] : 0.0f;

    // incoming state: theta_{s-1} = sum_{j=0..WIN-2} a^j * c[s-2-j]
    if (tid < 64) {
        float term = 0.0f;
        const int idx = s - 2 - tid;
        if (tid <= WIN - 2 && idx >= 0)
            term = exp2f((float)tid * l2a) * c[idx];
        #pragma unroll
        for (int off = 1; off <= 32; off <<= 1)
            term += __shfl_xor(term, off, 64);
        if (tid == 0) theta_sh = term;
    }

    sc[tid] = v;
    __syncthreads();
    const float theta_in = theta_sh;

    // inclusive Hillis-Steele scan, ratio a (squares each step)
    float Ad = a;
    for (int d = 1; d < CHUNK; d <<= 1) {
        const float self = sc[tid];
        const float prev = (tid >= d) ? sc[tid - d] : 0.0f;
        __syncthreads();
        sc[tid] = self + Ad * prev;
        __syncthreads();
        Ad *= Ad;
    }

    const float E = (tid > 0) ? sc[tid - 1] : 0.0f;
    float theta = exp2f((float)tid * l2a) * theta_in + E;
    theta = a * theta + v;
    if (t < T) out[t] = b + theta;
}

// ---------------------------------------------------------------------------
// Fallback: round-1 fused kernel (used only if workspace is too small).
// ---------------------------------------------------------------------------
#define RPI    64
#define NITER  ((WIN + CHUNK) / RPI)

__global__ __launch_bounds__(256) void dlm_fused(
    const float* __restrict__ X, const float* __restrict__ Z,
    const float* __restrict__ Gp,
    const float* __restrict__ eta, const float* __restrict__ zeta,
    const float* __restrict__ gam,
    float* __restrict__ out, int T)
{
    const int tid  = threadIdx.x;
    const int lane = tid & 63;
    const int wv   = tid >> 6;
    const int sub  = lane & 15;
    const int rsub = lane >> 4;
    const int s    = (int)blockIdx.x * CHUNK;

    __shared__ float cl[WIN + CHUNK];
    __shared__ float bl[CHUNK];
    __shared__ float sc[256];
    __shared__ float theta_sh;

    const float4 e4  = ((const float4*)eta)[sub];
    const float4 sz4 = ((const float4*)zeta)[sub];
    const float4 g4  = ((const float4*)gam)[sub];
    const float4* X4 = (const float4*)X;
    const float4* Z4 = (const float4*)Z;

    const float g   = *Gp;
    const float a   = 1.0f / (1.0f + expf(-g));
    const float l2a = log2f(a);

    for (int i = 0; i < NITER; ++i) {
        const int rb = s - WIN + i * RPI + wv * 16;
        float cp[4], bp[4];
        #pragma unroll
        for (int u = 0; u < 4; ++u) {
            const int r = rb + u * 4 + rsub;
            float4 z = make_float4(0.f, 0.f, 0.f, 0.f);
            float4 x = make_float4(0.f, 0.f, 0.f, 0.f);
            const bool in = (r >= 0) && (r < T);
            if (in)           z = Z4[(size_t)r * 16 + sub];
            if (in && i > 0)  x = X4[(size_t)r * 16 + sub];
            cp[u] = z.x*g4.x + z.y*g4.y + z.z*g4.z + z.w*g4.w;
            bp[u] = x.x*e4.x + x.y*e4.y + x.z*e4.z + x.w*e4.w
                  + z.x*sz4.x + z.y*sz4.y + z.z*sz4.z + z.w*sz4.w;
        }
        #pragma unroll
        for (int u = 0; u < 4; ++u) {
            #pragma unroll
            for (int off = 1; off <= 8; off <<= 1) {
                cp[u] += __shfl_xor(cp[u], off, 64);
                bp[u] += __shfl_xor(bp[u], off, 64);
            }
        }
        if (sub == 0) {
            #pragma unroll
            for (int u = 0; u < 4; ++u) {
                const int r = rb + u * 4 + rsub;
                cl[r - s + WIN] = cp[u];
                if (i > 0) bl[r - s] = bp[u];
            }
        }
    }
    __syncthreads();

    if (tid < 64) {
        float term = 0.0f;
        if (tid <= WIN - 2)
            term = exp2f((float)tid * l2a) * cl[WIN - 2 - tid];
        #pragma unroll
        for (int off = 1; off <= 32; off <<= 1)
            term += __shfl_xor(term, off, 64);
        if (tid == 0) theta_sh = term;
    }

    const int t = s + tid;
    const float v = (t == 0) ? 0.0f : cl[WIN + tid - 1];
    sc[tid] = v;
    __syncthreads();
    const float theta_in = theta_sh;

    float Ad = a;
    for (int d = 1; d < 256; d <<= 1) {
        const float self = sc[tid];
        const float prev = (tid >= d) ? sc[tid - d] : 0.0f;
        __syncthreads();
        sc[tid] = self + Ad * prev;
        __syncthreads();
        Ad *= Ad;
    }

    const float E = (tid > 0) ? sc[tid - 1] : 0.0f;
    float theta = exp2f((float)tid * l2a) * theta_in + E;
    theta = a * theta + v;
    if (t < T) out[t] = bl[tid] + theta;
}

extern "C" void kernel_launch(void* const* d_in, const int* in_sizes, int n_in,
                              void* d_out, int out_size, void* d_ws, size_t ws_size,
                              hipStream_t stream) {
    const float* X     = (const float*)d_in[0];
    const float* Z     = (const float*)d_in[1];
    const float* G     = (const float*)d_in[2];
    const float* eta   = (const float*)d_in[3];
    const float* zeta  = (const float*)d_in[4];
    const float* gamma = (const float*)d_in[5];
    float* out = (float*)d_out;

    const int T = in_sizes[0] / 64;
    const int nblk = (T + CHUNK - 1) / CHUNK;

    if (ws_size >= (size_t)T * sizeof(float)) {
        float* c_ws = (float*)d_ws;
        dlm_pass1<<<nblk, 256, 0, stream>>>(X, Z, eta, zeta, gamma, c_ws, out, T);
        dlm_pass2<<<nblk, 256, 0, stream>>>(c_ws, G, out, T);
    } else {
        dlm_fused<<<nblk, 256, 0, stream>>>(X, Z, G, eta, zeta, gamma, out, T);
    }
}

// Round 4
// 276.313 us; speedup vs baseline: 1.0217x; 1.0110x over previous
//
#include <hip/hip_runtime.h>

// DynamicLinearModel, two-pass version, round 4.
//
// theta_t = a*theta_{t-1} + c_{t-1},  a = sigmoid(G), c = Z@gamma, theta_0 = 0
// out_t   = theta_t + X_t@eta + Z_t@zeta
//
// Round-3 evidence: a PURE streaming GEMV (no scan, no window) still capped
// at ~2.5 TB/s effective with VGPR_Count=32 and ~0.2 loads in flight per
// wave: the compiler collapsed the software pipeline, and the 4-deep
// ds_swizzle (__shfl_xor) reduce chains parked every wave with zero loads
// outstanding ~90% of the time.
//
// Round-4 changes (pass 1 only):
//   1. 16-lane row reduce via DPP row_shr adds (VALU pipe, no DS latency):
//      4 back-to-back v_add_f32+DPP replace a 4-deep ds_swizzle chain.
//      Sum lands in lane 15 of each 16-lane row.
//   2. Hand-pipelined bursts with NAMED double buffers (zzA/zzB, xxA/xxB):
//      burst i+1's 8 float4 loads issue before burst i's reduce, keeping
//      8-16 loads in flight per thread. VGPR ~96 expected (the tell).
//   3. Bounds check by index clamp (min(r,T-1)) instead of cndmask'd data:
//      clamped rows never reach a stored output element.
//
// Pass 1: c[t] = Z[t].gamma -> ws;  b[t] = X[t].eta + Z[t].zeta -> out
// Pass 2: block-local scan over c (64-row geometric lookback, a^63 < 3e-9),
//         out[t] = b[t] + theta_t.

#define WIN    64
#define CHUNK  256

// ---- DPP 16-lane row sum: result in lane 15 of each 16-lane row ----------
template <int N>
__device__ __forceinline__ float rshr_add(float v) {
    const int s = __builtin_amdgcn_update_dpp(
        0, __float_as_int(v), 0x110 | N /*row_shr:N*/, 0xF, 0xF, true);
    return v + __int_as_float(s);
}
__device__ __forceinline__ float rsum16(float v) {
    v = rshr_add<8>(v);
    v = rshr_add<4>(v);
    v = rshr_add<2>(v);
    v = rshr_add<1>(v);
    return v;   // lane 15 of each row holds sum of all 16 lanes
}

// ---------------------------------------------------------------------------
// Pass 1: streaming GEMV. 16 lanes per row (1 KB coalesced wave-loads),
// double-buffered bursts, DPP reduce, single barrier, coalesced stores.
// ---------------------------------------------------------------------------
__global__ __launch_bounds__(256) void dlm_pass1(
    const float* __restrict__ X, const float* __restrict__ Z,
    const float* __restrict__ eta, const float* __restrict__ zeta,
    const float* __restrict__ gam,
    float* __restrict__ c_ws, float* __restrict__ b_out, int T)
{
    const int tid  = threadIdx.x;
    const int lane = tid & 63;
    const int wv   = tid >> 6;        // wave 0..3
    const int sub  = lane & 15;       // float4 index within a 64-float row
    const int rsub = lane >> 4;       // row within the 4-row group
    const int s    = (int)blockIdx.x * CHUNK;
    const int Tm1  = T - 1;

    __shared__ float cl[CHUNK];
    __shared__ float bl[CHUNK];

    const float4 e4  = ((const float4*)eta)[sub];
    const float4 sz4 = ((const float4*)zeta)[sub];
    const float4 g4  = ((const float4*)gam)[sub];
    const float4* X4 = (const float4*)X;
    const float4* Z4 = (const float4*)Z;

    float4 zzA[4], xxA[4], zzB[4], xxB[4];

    auto issue = [&](float4 (&zb)[4], float4 (&xb)[4], int i) {
        const int rb = s + i * 64 + wv * 16;
        #pragma unroll
        for (int u = 0; u < 4; ++u) {
            const int    r = min(rb + u * 4 + rsub, Tm1);
            const size_t o = (size_t)r * 16 + sub;
            zb[u] = Z4[o];
            xb[u] = X4[o];
        }
    };

    auto reduce_store = [&](const float4 (&zb)[4], const float4 (&xb)[4], int i) {
        float cp[4], bp[4];
        #pragma unroll
        for (int u = 0; u < 4; ++u) {
            const float4 z = zb[u], x = xb[u];
            cp[u] = z.x*g4.x + z.y*g4.y + z.z*g4.z + z.w*g4.w;
            bp[u] = x.x*e4.x + x.y*e4.y + x.z*e4.z + x.w*e4.w
                  + z.x*sz4.x + z.y*sz4.y + z.z*sz4.z + z.w*sz4.w;
            cp[u] = rsum16(cp[u]);
            bp[u] = rsum16(bp[u]);
        }
        if (sub == 15) {
            #pragma unroll
            for (int u = 0; u < 4; ++u) {
                const int idx = i * 64 + wv * 16 + u * 4 + rsub;
                cl[idx] = cp[u];
                bl[idx] = bp[u];
            }
        }
    };

    // 2-deep pipeline over the 4 bursts (CHUNK/64 == 4)
    issue(zzA, xxA, 0);
    issue(zzB, xxB, 1);
    reduce_store(zzA, xxA, 0);
    issue(zzA, xxA, 2);
    reduce_store(zzB, xxB, 1);
    issue(zzB, xxB, 3);
    reduce_store(zzA, xxA, 2);
    reduce_store(zzB, xxB, 3);

    __syncthreads();

    const int t = s + tid;
    if (t < T) {
        c_ws[t]  = cl[tid];
        b_out[t] = bl[tid];
    }
}

// ---------------------------------------------------------------------------
// Pass 2: per-block scan over materialized c (hot in L2/L3 from pass 1).
// ---------------------------------------------------------------------------
__global__ __launch_bounds__(256) void dlm_pass2(
    const float* __restrict__ c, const float* __restrict__ Gp,
    float* __restrict__ out, int T)
{
    const int tid = threadIdx.x;
    const int s   = (int)blockIdx.x * CHUNK;
    const int t   = s + tid;

    __shared__ float sc[CHUNK];
    __shared__ float theta_sh;

    const float g   = *Gp;
    const float a   = 1.0f / (1.0f + expf(-g));
    const float l2a = log2f(a);

    // v_t = c[t-1], v_0 = 0; b read up front (own element only, no hazard)
    const float v = (t >= 1 && t < T) ? c[t - 1] : 0.0f;
    const float b = (t < T) ? out[t] : 0.0f;

    // incoming state: theta_{s-1} = sum_{j=0..WIN-2} a^j * c[s-2-j]
    if (tid < 64) {
        float term = 0.0f;
        const int idx = s - 2 - tid;
        if (tid <= WIN - 2 && idx >= 0)
            term = exp2f((float)tid * l2a) * c[idx];
        #pragma unroll
        for (int off = 1; off <= 32; off <<= 1)
            term += __shfl_xor(term, off, 64);
        if (tid == 0) theta_sh = term;
    }

    sc[tid] = v;
    __syncthreads();
    const float theta_in = theta_sh;

    // inclusive Hillis-Steele scan, ratio a (squares each step)
    float Ad = a;
    for (int d = 1; d < CHUNK; d <<= 1) {
        const float self = sc[tid];
        const float prev = (tid >= d) ? sc[tid - d] : 0.0f;
        __syncthreads();
        sc[tid] = self + Ad * prev;
        __syncthreads();
        Ad *= Ad;
    }

    const float E = (tid > 0) ? sc[tid - 1] : 0.0f;
    float theta = exp2f((float)tid * l2a) * theta_in + E;
    theta = a * theta + v;
    if (t < T) out[t] = b + theta;
}

// ---------------------------------------------------------------------------
// Fallback: round-1 fused kernel (used only if workspace is too small).
// ---------------------------------------------------------------------------
#define RPI    64
#define NITER  ((WIN + CHUNK) / RPI)

__global__ __launch_bounds__(256) void dlm_fused(
    const float* __restrict__ X, const float* __restrict__ Z,
    const float* __restrict__ Gp,
    const float* __restrict__ eta, const float* __restrict__ zeta,
    const float* __restrict__ gam,
    float* __restrict__ out, int T)
{
    const int tid  = threadIdx.x;
    const int lane = tid & 63;
    const int wv   = tid >> 6;
    const int sub  = lane & 15;
    const int rsub = lane >> 4;
    const int s    = (int)blockIdx.x * CHUNK;

    __shared__ float cl[WIN + CHUNK];
    __shared__ float bl[CHUNK];
    __shared__ float sc[256];
    __shared__ float theta_sh;

    const float4 e4  = ((const float4*)eta)[sub];
    const float4 sz4 = ((const float4*)zeta)[sub];
    const float4 g4  = ((const float4*)gam)[sub];
    const float4* X4 = (const float4*)X;
    const float4* Z4 = (const float4*)Z;

    const float g   = *Gp;
    const float a   = 1.0f / (1.0f + expf(-g));
    const float l2a = log2f(a);

    for (int i = 0; i < NITER; ++i) {
        const int rb = s - WIN + i * RPI + wv * 16;
        float cp[4], bp[4];
        #pragma unroll
        for (int u = 0; u < 4; ++u) {
            const int r = rb + u * 4 + rsub;
            float4 z = make_float4(0.f, 0.f, 0.f, 0.f);
            float4 x = make_float4(0.f, 0.f, 0.f, 0.f);
            const bool in = (r >= 0) && (r < T);
            if (in)           z = Z4[(size_t)r * 16 + sub];
            if (in && i > 0)  x = X4[(size_t)r * 16 + sub];
            cp[u] = z.x*g4.x + z.y*g4.y + z.z*g4.z + z.w*g4.w;
            bp[u] = x.x*e4.x + x.y*e4.y + x.z*e4.z + x.w*e4.w
                  + z.x*sz4.x + z.y*sz4.y + z.z*sz4.z + z.w*sz4.w;
        }
        #pragma unroll
        for (int u = 0; u < 4; ++u) {
            #pragma unroll
            for (int off = 1; off <= 8; off <<= 1) {
                cp[u] += __shfl_xor(cp[u], off, 64);
                bp[u] += __shfl_xor(bp[u], off, 64);
            }
        }
        if (sub == 0) {
            #pragma unroll
            for (int u = 0; u < 4; ++u) {
                const int r = rb + u * 4 + rsub;
                cl[r - s + WIN] = cp[u];
                if (i > 0) bl[r - s] = bp[u];
            }
        }
    }
    __syncthreads();

    if (tid < 64) {
        float term = 0.0f;
        if (tid <= WIN - 2)
            term = exp2f((float)tid * l2a) * cl[WIN - 2 - tid];
        #pragma unroll
        for (int off = 1; off <= 32; off <<= 1)
            term += __shfl_xor(term, off, 64);
        if (tid == 0) theta_sh = term;
    }

    const int t = s + tid;
    const float v = (t == 0) ? 0.0f : cl[WIN + tid - 1];
    sc[tid] = v;
    __syncthreads();
    const float theta_in = theta_sh;

    float Ad = a;
    for (int d = 1; d < 256; d <<= 1) {
        const float self = sc[tid];
        const float prev = (tid >= d) ? sc[tid - d] : 0.0f;
        __syncthreads();
        sc[tid] = self + Ad * prev;
        __syncthreads();
        Ad *= Ad;
    }

    const float E = (tid > 0) ? sc[tid - 1] : 0.0f;
    float theta = exp2f((float)tid * l2a) * theta_in + E;
    theta = a * theta + v;
    if (t < T) out[t] = bl[tid] + theta;
}

extern "C" void kernel_launch(void* const* d_in, const int* in_sizes, int n_in,
                              void* d_out, int out_size, void* d_ws, size_t ws_size,
                              hipStream_t stream) {
    const float* X     = (const float*)d_in[0];
    const float* Z     = (const float*)d_in[1];
    const float* G     = (const float*)d_in[2];
    const float* eta   = (const float*)d_in[3];
    const float* zeta  = (const float*)d_in[4];
    const float* gamma = (const float*)d_in[5];
    float* out = (float*)d_out;

    const int T = in_sizes[0] / 64;
    const int nblk = (T + CHUNK - 1) / CHUNK;

    if (ws_size >= (size_t)T * sizeof(float)) {
        float* c_ws = (float*)d_ws;
        dlm_pass1<<<nblk, 256, 0, stream>>>(X, Z, eta, zeta, gamma, c_ws, out, T);
        dlm_pass2<<<nblk, 256, 0, stream>>>(c_ws, G, out, T);
    } else {
        dlm_fused<<<nblk, 256, 0, stream>>>(X, Z, G, eta, zeta, gamma, out, T);
    }
}